// Round 4
// baseline (401.358 us; speedup 1.0000x reference)
//
#include <hip/hip_runtime.h>

// AdEx neuron simulation: T=500 steps, N=100000 neurons.
// R7 = R6 with the compile error fixed: __builtin_nontemporal_store rejects
// HIP's float2 (a class, not a clang vector). Use a native clang
// ext_vector_type(2) float for all 8B loads/stores instead.
// (R4/R5's "container failed twice" was almost certainly this same compile
// failure surfacing as an infra error.)
//
// Design vs R3 (130 us rocprof, VALUBusy 40%, Occ 17%, 29% HBM):
//  Latency-bound diagnosis: 1563 waves -> 1.5 waves/SIMD, each wave a fully
//  serial per-step dependency chain (zero intra-thread ILP) -> SIMD idles 60%.
//  1. TWO neurons per thread (adjacent, 8B vector ld/st): two independent
//     recurrence chains interleaved in-register per wave. Halves VMEM instr
//     count; 8B/lane coalescing sweet spot. 782 waves (~3/CU) but each wave
//     can issue ~2x more densely during chain stalls.
//  2. Single running byte-offset register: stores use base `out`, main-loop
//     loads use base `I + DEPTH*rowBytes` (SGPR), one v_add per step.
//  3. Per-neuron math is bit-identical to R3 (same ops, same order) ->
//     absmax must stay 4.8828e-4.
// Numerics: contract(off), left-to-right order, precise expf (exp2-fold
// shortcut deferred: absmax margin only 3.4x).

#define DEPTH 12

typedef float f32x2 __attribute__((ext_vector_type(2)));
typedef int   i32x2 __attribute__((ext_vector_type(2)));

__global__ __launch_bounds__(64) void adex_kernel(
    const float* __restrict__ I,
    const float* __restrict__ v0,
    const float* __restrict__ c0,
    const int*   __restrict__ ref0,
    float*       __restrict__ out,
    int N, int T)
{
#pragma clang fp contract(off)
    const float EL       = (float)(-70.6e-3);
    const float VT       = (float)(-50.4e-3);
    const float DELTAT   = (float)(2e-3);
    const float R_DELTAT = (float)(1.0 / (double)((float)(2e-3)));  // fl(1/d)
    const float NEG_GL   = (float)(-30e-9);
    const float GLDT     = (float)(30e-9 * 2e-3);        // GL*DELTAT
    const float DT_CM    = (float)(1e-3 / 281e-12);      // DT/CM
    const float DT_TAUW  = (float)(1e-3 / 144e-3);       // DT/TAUW
    const float Af       = (float)(4e-9);
    const float Bf       = (float)(0.0805e-9);
    const int   REF_STEPS = 2;

    int tid = blockIdx.x * blockDim.x + threadIdx.x;
    int n2  = tid * 2;
    if (n2 >= N) return;

    const unsigned stride_b = (unsigned)N * 4u;

    // One simulation step for one neuron. Same op order as R3.
    auto step = [&](float& v_, float& c_, int& rf_, float It) -> float {
        bool  in_ref = rf_ > 0;
        float v_eff  = in_ref ? EL : v_;

        // arg = (v_eff - VT) / DELTAT  — Newton/fma faithful division
        float x   = v_eff - VT;
        float y0  = x * R_DELTAT;
        float e   = fmaf(-DELTAT, y0, x);
        float arg = fmaf(e, R_DELTAT, y0);
        arg = fminf(arg, 15.0f);
        float exp_term = GLDT * expf(arg);

        float acc = NEG_GL * (v_eff - EL);
        acc = acc + exp_term;
        acc = acc - c_;
        acc = acc + It;
        float dv = DT_CM * acc;

        float v_new = in_ref ? EL : (v_eff + dv);
        float c_new = c_ + DT_TAUW * ((Af * (v_eff - EL)) - c_);

        bool  spike = v_new >= VT;
        float v_out = spike ? EL : v_new;

        c_  = spike ? (c_new + Bf) : c_new;
        rf_ = spike ? REF_STEPS : (in_ref ? rf_ - 1 : 0);
        v_  = v_out;
        return v_out;
    };

    if (n2 + 1 < N) {
        // ---- vector path: neurons n2, n2+1 (8B vector; n2 even -> aligned) ----
        f32x2 vv = *reinterpret_cast<const f32x2*>(v0 + n2);
        f32x2 cc = *reinterpret_cast<const f32x2*>(c0 + n2);
        i32x2 rr = *reinterpret_cast<const i32x2*>(ref0 + n2);
        float v_0 = vv.x, v_1 = vv.y;
        float c_0 = cc.x, c_1 = cc.y;
        int   r_0 = rr.x, r_1 = rr.y;

        unsigned off = (unsigned)n2 * 4u;   // running byte offset (store base)

        if (T >= 2 * DEPTH) {
            // Load base shifted by DEPTH rows: load at `off` = timestep t+DEPTH.
            const char* Ip = (const char*)I + (size_t)DEPTH * (size_t)stride_b;

            f32x2 buf[DEPTH];
            {
                unsigned poff = off;
#pragma unroll
                for (int k = 0; k < DEPTH; ++k) {
                    buf[k] = *reinterpret_cast<const f32x2*>((const char*)I + poff);
                    poff += stride_b;
                }
            }

            int t = 0;
            // Main loop: consume buf[j] (timestep t+j), prefetch t+j+DEPTH.
            for (; t + 2 * DEPTH <= T; t += DEPTH) {
#pragma unroll
                for (int j = 0; j < DEPTH; ++j) {
                    f32x2 It = buf[j];
                    buf[j] = *reinterpret_cast<const f32x2*>(Ip + off);
                    f32x2 r;
                    r.x = step(v_0, c_0, r_0, It.x);
                    r.y = step(v_1, c_1, r_1, It.y);
                    __builtin_nontemporal_store(r, reinterpret_cast<f32x2*>((char*)out + off));
                    off += stride_b;
                }
            }

            // Epilogue: DEPTH..2*DEPTH-1 remaining steps, predicated loads.
#pragma unroll
            for (int j = 0; j < 2 * DEPTH; ++j) {
                if (t + j < T) {
                    f32x2 It = buf[j % DEPTH];
                    if (t + j + DEPTH < T) {
                        buf[j % DEPTH] = *reinterpret_cast<const f32x2*>(Ip + off);
                    }
                    f32x2 r;
                    r.x = step(v_0, c_0, r_0, It.x);
                    r.y = step(v_1, c_1, r_1, It.y);
                    __builtin_nontemporal_store(r, reinterpret_cast<f32x2*>((char*)out + off));
                    off += stride_b;
                }
            }
        } else {
            // Tiny-T fallback (not hit at T=500): simple unpipelined loop.
            for (int tt = 0; tt < T; ++tt) {
                f32x2 It = *reinterpret_cast<const f32x2*>((const char*)I + off);
                f32x2 r;
                r.x = step(v_0, c_0, r_0, It.x);
                r.y = step(v_1, c_1, r_1, It.y);
                __builtin_nontemporal_store(r, reinterpret_cast<f32x2*>((char*)out + off));
                off += stride_b;
            }
        }
    } else {
        // ---- scalar tail: only reached when N is odd (last neuron) ----
        float v_ = v0[n2];
        float c_ = c0[n2];
        int   r_ = ref0[n2];
        for (int tt = 0; tt < T; ++tt) {
            float It = I[(size_t)tt * (size_t)N + (size_t)n2];
            float r  = step(v_, c_, r_, It);
            __builtin_nontemporal_store(r, out + (size_t)tt * (size_t)N + (size_t)n2);
        }
    }
}

extern "C" void kernel_launch(void* const* d_in, const int* in_sizes, int n_in,
                              void* d_out, int out_size, void* d_ws, size_t ws_size,
                              hipStream_t stream) {
    const float* I    = (const float*)d_in[0];
    const float* v0   = (const float*)d_in[1];
    const float* c0   = (const float*)d_in[2];
    const int*   ref0 = (const int*)d_in[3];
    float*       out  = (float*)d_out;

    int N = in_sizes[1];            // 100000
    int T = in_sizes[0] / N;        // 500

    int nThreads = (N + 1) / 2;     // one thread per neuron PAIR
    dim3 block(64);
    dim3 grid((nThreads + 63) / 64);  // 782 one-wave blocks, ~3 waves/CU
    adex_kernel<<<grid, block, 0, stream>>>(I, v0, c0, ref0, out, N, T);
}

// Round 5
// 363.688 us; speedup vs baseline: 1.1036x; 1.1036x over previous
//
#include <hip/hip_runtime.h>

// AdEx neuron simulation: T=500 steps, N=100000 neurons. One thread per neuron.
// R8: revert R7's 2-neurons/thread (REGRESSED 130->175 us: halving waves to
// 0.76/SIMD exposed per-wave stall; total VALU issue-cycles unchanged).
// Little's-law fit of R3/R7: dur == T * L_eff/DEPTH with in-flight read bytes
// capped at waves*DEPTH*bytes (4.8 MB both) -> MLP-starved, not chain-bound.
//  - R3: 624 cyc/step = 3.1us latency / 12-deep ring  (exact match)
//  - R7: 838 cyc/step = 4.2us latency / 12-deep ring  (exact match)
// Lever: more bytes in flight per wave. DEPTH 12 -> 24 (24 loads + 24 stores
// interleaved = 48 outstanding VMEM, under the vmcnt=63 ceiling; DEPTH=32
// would overflow -> conservative waits). VGPR ~52, still wave-count-limited.
// Single running byte offset: store base `out`, load base `I + DEPTH rows`.
// Per-neuron math bit-identical to R3 -> absmax must stay 4.8828e-4.
// Numerics: contract(off), left-to-right order, precise expf.

#define DEPTH 24

__global__ __launch_bounds__(64) void adex_kernel(
    const float* __restrict__ I,
    const float* __restrict__ v0,
    const float* __restrict__ c0,
    const int*   __restrict__ ref0,
    float*       __restrict__ out,
    int N, int T)
{
#pragma clang fp contract(off)
    const float EL       = (float)(-70.6e-3);
    const float VT       = (float)(-50.4e-3);
    const float DELTAT   = (float)(2e-3);
    const float R_DELTAT = (float)(1.0 / (double)((float)(2e-3)));  // fl(1/d)
    const float NEG_GL   = (float)(-30e-9);
    const float GLDT     = (float)(30e-9 * 2e-3);        // GL*DELTAT
    const float DT_CM    = (float)(1e-3 / 281e-12);      // DT/CM
    const float DT_TAUW  = (float)(1e-3 / 144e-3);       // DT/TAUW
    const float Af       = (float)(4e-9);
    const float Bf       = (float)(0.0805e-9);
    const int   REF_STEPS = 2;

    int n = blockIdx.x * blockDim.x + threadIdx.x;
    if (n >= N) return;

    float v  = v0[n];
    float c  = c0[n];
    int   rf = ref0[n];

    const unsigned stride_b = (unsigned)N * 4u;

    // One simulation step. Updates v, c, rf; returns v_out. Same op order as R3.
    auto step = [&](float It) -> float {
        bool  in_ref = rf > 0;
        float v_eff  = in_ref ? EL : v;

        // arg = (v_eff - VT) / DELTAT  — Newton/fma faithful division
        float x   = v_eff - VT;
        float y0  = x * R_DELTAT;
        float e   = fmaf(-DELTAT, y0, x);
        float arg = fmaf(e, R_DELTAT, y0);
        arg = fminf(arg, 15.0f);
        float exp_term = GLDT * expf(arg);

        float acc = NEG_GL * (v_eff - EL);
        acc = acc + exp_term;
        acc = acc - c;
        acc = acc + It;
        float dv = DT_CM * acc;

        float v_new = in_ref ? EL : (v_eff + dv);
        float c_new = c + DT_TAUW * ((Af * (v_eff - EL)) - c);

        bool  spike = v_new >= VT;
        float v_out = spike ? EL : v_new;

        c  = spike ? (c_new + Bf) : c_new;
        rf = spike ? REF_STEPS : (in_ref ? rf - 1 : 0);
        v  = v_out;
        return v_out;
    };

    unsigned off = (unsigned)n * 4u;   // running byte offset (store base `out`)

    if (T >= 2 * DEPTH) {
        // Load base shifted by DEPTH rows: load at `off` fetches timestep
        // (store-step + DEPTH). One offset register for both streams.
        const char* Ip = (const char*)I + (size_t)DEPTH * (size_t)stride_b;

        float buf[DEPTH];
        {
            unsigned poff = off;
#pragma unroll
            for (int k = 0; k < DEPTH; ++k) {
                buf[k] = *(const float*)((const char*)I + poff);
                poff += stride_b;
            }
        }

        int t = 0;
        // Main loop: consume buf[j] (timestep t+j, loaded DEPTH steps ago),
        // prefetch timestep t+j+DEPTH into the same slot. Static ring indices.
        for (; t + 2 * DEPTH <= T; t += DEPTH) {
#pragma unroll
            for (int j = 0; j < DEPTH; ++j) {
                float It = buf[j];
                buf[j] = *(const float*)(Ip + off);
                float v_out = step(It);
                __builtin_nontemporal_store(v_out, (float*)((char*)out + off));
                off += stride_b;
            }
        }

        // Epilogue: DEPTH..2*DEPTH-1 remaining steps, predicated loads.
#pragma unroll
        for (int j = 0; j < 2 * DEPTH; ++j) {
            if (t + j < T) {
                float It = buf[j % DEPTH];
                if (t + j + DEPTH < T) {
                    buf[j % DEPTH] = *(const float*)(Ip + off);
                }
                float v_out = step(It);
                __builtin_nontemporal_store(v_out, (float*)((char*)out + off));
                off += stride_b;
            }
        }
    } else {
        // Tiny-T fallback (not hit at T=500): simple unpipelined loop.
        for (int tt = 0; tt < T; ++tt) {
            float It = *(const float*)((const char*)I + off);
            float v_out = step(It);
            __builtin_nontemporal_store(v_out, (float*)((char*)out + off));
            off += stride_b;
        }
    }
}

extern "C" void kernel_launch(void* const* d_in, const int* in_sizes, int n_in,
                              void* d_out, int out_size, void* d_ws, size_t ws_size,
                              hipStream_t stream) {
    const float* I    = (const float*)d_in[0];
    const float* v0   = (const float*)d_in[1];
    const float* c0   = (const float*)d_in[2];
    const int*   ref0 = (const int*)d_in[3];
    float*       out  = (float*)d_out;

    int N = in_sizes[1];            // 100000
    int T = in_sizes[0] / N;        // 500

    dim3 block(64);
    dim3 grid((N + 63) / 64);       // 1563 one-wave blocks -> 6-7 waves/CU
    adex_kernel<<<grid, block, 0, stream>>>(I, v0, c0, ref0, out, N, T);
}